// Round 9
// baseline (219.720 us; speedup 1.0000x reference)
//
#include <hip/hip_runtime.h>
#include <hip/hip_bf16.h>

// LogoAwareAttention: B=8, N=1024, C=768, H=12, Dh=64.
// Per-(b,h) scalar logit bias cancels in softmax -> dropped.
// Softmax without max-subtraction (scores bounded; shift-invariant).
//
// R9 changes (evidence: R8 gemm0 53.7us latency-bound, no pipe >35%; xb
// round-trip (conv kernel + 25MB traffic) is pure overhead):
//  1. gemm0 MODE0 reads x fp32 directly: A staged via 2-deep register
//     prefetch + convert + ds_write (pitch 36); B keeps async-DMA dbuf.
//     xb buffer and the 6144-block conv in k_prep are eliminated.
//  2. k_prep is now transposes only (576 blocks).

typedef __bf16 b16x8 __attribute__((ext_vector_type(8)));
typedef float f32x4 __attribute__((ext_vector_type(4)));

__device__ __forceinline__ ushort f2b(float f) {
    union { float f; uint u; } v; v.f = f;
    uint u = v.u;
    u += 0x7fffu + ((u >> 16) & 1u);   // round-to-nearest-even
    return (ushort)(u >> 16);
}

__device__ __forceinline__ uint packbf(float a, float b) {
    union { float f; uint u; } ua, ub; ua.f = a; ub.f = b;
    return ((ua.u + 0x8000u) >> 16) | ((ub.u + 0x8000u) & 0xffff0000u);
}

// async 16B-per-lane global->LDS copy; lds dest = wave-uniform base + lane*16
__device__ __forceinline__ void async_cp16(const void* g, void* l) {
    __builtin_amdgcn_global_load_lds(
        (const __attribute__((address_space(1))) unsigned int*)g,
        (__attribute__((address_space(3))) unsigned int*)l, 16, 0, 0);
}

// ---------------- prep: weight transposes only ----------------
// blocks [0,432): Wqkv^T;  [432,576): Wproj^T.

__global__ __launch_bounds__(256)
void k_prep(const float* __restrict__ Wqkv, ushort* __restrict__ wqkvt,
            const float* __restrict__ Wproj, ushort* __restrict__ wprojt) {
    __shared__ ushort T[64][65];
    const int blk = blockIdx.x;
    const int t   = threadIdx.x;
    const bool isqkv = (blk < 432);
    const int idx = isqkv ? blk : (blk - 432);
    const int Nin = isqkv ? 2304 : 768;
    const float* W  = isqkv ? Wqkv : Wproj;
    ushort* Wt      = isqkv ? wqkvt : wprojt;
    const int k0 = (idx % 12) * 64;
    const int n0 = (idx / 12) * 64;
    const int r  = t >> 4, cg = (t & 15) * 4;
    #pragma unroll
    for (int rr = 0; rr < 64; rr += 16) {
        const float4 v = *reinterpret_cast<const float4*>(&W[(size_t)(k0 + r + rr) * Nin + n0 + cg]);
        T[r + rr][cg + 0] = f2b(v.x); T[r + rr][cg + 1] = f2b(v.y);
        T[r + rr][cg + 2] = f2b(v.z); T[r + rr][cg + 3] = f2b(v.w);
    }
    __syncthreads();
    #pragma unroll
    for (int rr = 0; rr < 64; rr += 16) {
        ushort4 o;
        o.x = T[cg + 0][r + rr]; o.y = T[cg + 1][r + rr];
        o.z = T[cg + 2][r + rr]; o.w = T[cg + 3][r + rr];
        *reinterpret_cast<ushort4*>(&Wt[(size_t)(n0 + r + rr) * 768 + k0 + cg]) = o;
    }
}

// ---------------- GEMM: 128x128 tile, BK=32, dbuf, XCD swizzle, C^T epilogue ----------
// MODE 0: A = x fp32 (convert-in-staging, 2-deep reg prefetch, ds_write, pitch 36);
//         B = Wqkv^T bf16 (async DMA dbuf). Epilogue scatters q/k (ushort4) + v^T.
// MODE 1: A = ao bf16 (async DMA), B = Wproj^T; fp32 C + bias.

template<int MODE>
__global__ __launch_bounds__(256, 2)
void k_gemm(const float* __restrict__ Af, const ushort* __restrict__ Ab,
            const ushort* __restrict__ Bt,
            ushort* __restrict__ qo, ushort* __restrict__ ko, ushort* __restrict__ vo,
            float* __restrict__ co, const float* __restrict__ bias,
            int M, int N, int K) {
    constexpr int SA = (MODE == 0) ? 36 : 32;     // A LDS pitch
    __shared__ ushort As[2][128 * 36];
    __shared__ ushort Bs[2][128 * 32];
    const int id   = blockIdx.x;
    const int xcd  = id & 7;
    const int s    = id >> 3;
    const int by   = xcd * 8 + (s & 7);
    const int bx   = s >> 3;
    const int tid  = threadIdx.x;
    const int lane = tid & 63;
    const int w    = tid >> 6;
    const int wm   = w >> 1, wn = w & 1;
    const int m16  = lane & 15, quad = lane >> 4;
    const int mbase = by * 128, nbase = bx * 128;

    f32x4 acc[4][4];
    #pragma unroll
    for (int i = 0; i < 4; i++)
        #pragma unroll
        for (int j = 0; j < 4; j++) acc[i][j] = (f32x4){0.f, 0.f, 0.f, 0.f};

    // ---- B staging geometry (async DMA, both modes) ----
    const int rS = w * 32 + (lane >> 2);
    const int cS = (lane & 3) * 8;
    const int wOff0 = (w * 2 + 0) * 512;
    const int wOff1 = (w * 2 + 1) * 512;
    const ushort* gB0 = &Bt[(size_t)(nbase + rS)      * K + cS];
    const ushort* gB1 = &Bt[(size_t)(nbase + rS + 16) * K + cS];

    // ---- A staging geometry ----
    // MODE 0: thread t -> row rA=t>>1, col half cA=(t&1)*16; 4 float4 loads.
    const int rA = tid >> 1, cA = (tid & 1) * 16;
    const float*  gAf = (MODE == 0) ? &Af[(size_t)(mbase + rA) * K + cA] : nullptr;
    const ushort* gA0 = (MODE == 1) ? &Ab[(size_t)(mbase + rS)      * K + cS] : nullptr;
    const ushort* gA1 = (MODE == 1) ? &Ab[(size_t)(mbase + rS + 16) * K + cS] : nullptr;

    float4 pf[4];
    if (MODE == 0) {
        // stage tile 0 synchronously into buf0
        #pragma unroll
        for (int i = 0; i < 4; i++) pf[i] = *reinterpret_cast<const float4*>(gAf + i * 4);
        #pragma unroll
        for (int i = 0; i < 4; i++) {
            ushort4 o;
            o.x = f2b(pf[i].x); o.y = f2b(pf[i].y); o.z = f2b(pf[i].z); o.w = f2b(pf[i].w);
            *reinterpret_cast<ushort4*>(&As[0][rA * SA + cA + i * 4]) = o;
        }
        // prefetch tile 1 into regs
        #pragma unroll
        for (int i = 0; i < 4; i++) pf[i] = *reinterpret_cast<const float4*>(gAf + 32 + i * 4);
    } else {
        async_cp16(gA0, &As[0][wOff0]);
        async_cp16(gA1, &As[0][wOff1]);
    }
    async_cp16(gB0, &Bs[0][wOff0]);
    async_cp16(gB1, &Bs[0][wOff1]);

    for (int kt = 0; kt < K; kt += 32) {
        const int cur = (kt >> 5) & 1, nxt = cur ^ 1;
        __syncthreads();    // buf[cur] complete; buf[nxt] readers done
        if (kt + 32 < K) {
            async_cp16(gB0 + kt + 32, &Bs[nxt][wOff0]);
            async_cp16(gB1 + kt + 32, &Bs[nxt][wOff1]);
            if (MODE == 0) {
                #pragma unroll
                for (int i = 0; i < 4; i++) {
                    ushort4 o;
                    o.x = f2b(pf[i].x); o.y = f2b(pf[i].y);
                    o.z = f2b(pf[i].z); o.w = f2b(pf[i].w);
                    *reinterpret_cast<ushort4*>(&As[nxt][rA * SA + cA + i * 4]) = o;
                }
                if (kt + 64 < K) {
                    #pragma unroll
                    for (int i = 0; i < 4; i++)
                        pf[i] = *reinterpret_cast<const float4*>(gAf + kt + 64 + i * 4);
                }
            } else {
                async_cp16(gA0 + kt + 32, &As[nxt][wOff0]);
                async_cp16(gA1 + kt + 32, &As[nxt][wOff1]);
            }
        }

        b16x8 af[4], bf[4];
        #pragma unroll
        for (int i = 0; i < 4; i++)
            af[i] = *reinterpret_cast<const b16x8*>(&As[cur][(wm * 64 + i * 16 + m16) * SA + quad * 8]);
        #pragma unroll
        for (int j = 0; j < 4; j++)
            bf[j] = *reinterpret_cast<const b16x8*>(&Bs[cur][(wn * 64 + j * 16 + m16) * 32 + quad * 8]);
        #pragma unroll
        for (int i = 0; i < 4; i++)
            #pragma unroll
            for (int j = 0; j < 4; j++)
                acc[i][j] = __builtin_amdgcn_mfma_f32_16x16x32_bf16(bf[j], af[i], acc[i][j], 0, 0, 0);
    }

    // epilogue: C^T -> feature f0+r, token tok
    #pragma unroll
    for (int j = 0; j < 4; j++) {
        const int f0 = nbase + wn * 64 + j * 16 + quad * 4;
        #pragma unroll
        for (int i = 0; i < 4; i++) {
            const int tok = mbase + wm * 64 + i * 16 + m16;
            const int b = tok >> 10, n = tok & 1023;
            if (MODE == 0) {
                const int sp  = f0 / 768;
                const int rem = f0 - sp * 768;
                const int h   = rem >> 6;
                const int d0  = rem & 63;
                if (sp < 2) {
                    ushort4 pk;
                    pk.x = f2b(acc[i][j][0]); pk.y = f2b(acc[i][j][1]);
                    pk.z = f2b(acc[i][j][2]); pk.w = f2b(acc[i][j][3]);
                    ushort* base = (sp == 0) ? qo : ko;
                    *reinterpret_cast<ushort4*>(
                        &base[((size_t)(b * 12 + h) * 1024 + n) * 64 + d0]) = pk;
                } else {
                    #pragma unroll
                    for (int r = 0; r < 4; r++)
                        vo[((size_t)(b * 12 + h) * 64 + d0 + r) * 1024 + n] =
                            f2b(acc[i][j][r]);
                }
            } else {
                float4 val;
                val.x = acc[i][j][0] + bias[f0 + 0];
                val.y = acc[i][j][1] + bias[f0 + 1];
                val.z = acc[i][j][2] + bias[f0 + 2];
                val.w = acc[i][j][3] + bias[f0 + 3];
                *reinterpret_cast<float4*>(&co[(size_t)tok * N + f0]) = val;
            }
        }
    }
}

// ---------------- attention: flash, LDS-staged K/V, Q-blocked x2 (unchanged) ----------

#define AP 72   // LDS row pitch (elements)

__global__ __launch_bounds__(256)
void k_attn(const ushort* __restrict__ qa, const ushort* __restrict__ ka,
            const ushort* __restrict__ vt, ushort* __restrict__ ao) {
    __shared__ ushort Ks[64 * AP];
    __shared__ ushort Vs[64 * AP];

    const int l    = blockIdx.x;               // 0..767
    const int xcd  = l & 7;
    const int g    = l >> 3;                   // 0..95
    const int head = (g % 12) * 8 + xcd;       // head%8 == xcd -> XCD locality
    const int qsup = g / 12;                   // 0..7 (128-row supertile)
    const int tid  = threadIdx.x;
    const int w    = tid >> 6;
    const int lane = tid & 63;
    const int n    = lane & 15;
    const int q    = lane >> 4;

    const ushort* qh = qa + (size_t)head * 65536;
    const ushort* kh = ka + (size_t)head * 65536;
    const ushort* vh = vt + (size_t)head * 65536;
    const int qrow0 = qsup * 128 + w * 32;

    b16x8 bq0[2], bq1[2];
    #pragma unroll
    for (int u = 0; u < 2; u++) {
        bq0[u] = *reinterpret_cast<const b16x8*>(&qh[(qrow0 + u * 16 + n) * 64 + q * 8]);
        bq1[u] = *reinterpret_cast<const b16x8*>(&qh[(qrow0 + u * 16 + n) * 64 + 32 + q * 8]);
    }

    const int kr0 = tid >> 3, kc0 = (tid & 7) * 8;
    const int kr1 = kr0 + 32, kc1 = kc0;

    int4 kg0, kg1, vg0, vg1;
    kg0 = *reinterpret_cast<const int4*>(&kh[(0 + kr0) * 64 + kc0]);
    kg1 = *reinterpret_cast<const int4*>(&kh[(0 + kr1) * 64 + kc1]);
    vg0 = *reinterpret_cast<const int4*>(&vh[kr0 * 1024 + 0 + kc0]);
    vg1 = *reinterpret_cast<const int4*>(&vh[kr1 * 1024 + 0 + kc1]);

    f32x4 o[2][4];
    #pragma unroll
    for (int u = 0; u < 2; u++)
        #pragma unroll
        for (int dt = 0; dt < 4; dt++) o[u][dt] = (f32x4){0, 0, 0, 0};
    float Lacc[2] = {0.f, 0.f};

    const float SC = 0.125f * 1.4426950408889634f;
    const int s0 = ((q & 1) * 2) * 16 + n;
    const int s1 = s0 + 16;
    const bool lowq = (q < 2);

    for (int m0 = 0; m0 < 1024; m0 += 64) {
        *reinterpret_cast<int4*>(&Ks[kr0 * AP + kc0]) = kg0;
        *reinterpret_cast<int4*>(&Ks[kr1 * AP + kc1]) = kg1;
        *reinterpret_cast<int4*>(&Vs[kr0 * AP + kc0]) = vg0;
        *reinterpret_cast<int4*>(&Vs[kr1 * AP + kc1]) = vg1;
        __syncthreads();

        if (m0 + 64 < 1024) {
            kg0 = *reinterpret_cast<const int4*>(&kh[(m0 + 64 + kr0) * 64 + kc0]);
            kg1 = *reinterpret_cast<const int4*>(&kh[(m0 + 64 + kr1) * 64 + kc1]);
            vg0 = *reinterpret_cast<const int4*>(&vh[kr0 * 1024 + m0 + 64 + kc0]);
            vg1 = *reinterpret_cast<const int4*>(&vh[kr1 * 1024 + m0 + 64 + kc1]);
        }

        #pragma unroll
        for (int mc = 0; mc < 2; mc++) {
            b16x8 ka0t[2], ka1t[2];
            #pragma unroll
            for (int t = 0; t < 2; t++) {
                ka0t[t] = *reinterpret_cast<const b16x8*>(&Ks[(mc * 32 + t * 16 + n) * AP + q * 8]);
                ka1t[t] = *reinterpret_cast<const b16x8*>(&Ks[(mc * 32 + t * 16 + n) * AP + 32 + q * 8]);
            }
            f32x4 st[2][2];
            #pragma unroll
            for (int u = 0; u < 2; u++)
                #pragma unroll
                for (int t = 0; t < 2; t++) {
                    st[u][t] = (f32x4){0, 0, 0, 0};
                    st[u][t] = __builtin_amdgcn_mfma_f32_16x16x32_bf16(ka0t[t], bq0[u], st[u][t], 0, 0, 0);
                    st[u][t] = __builtin_amdgcn_mfma_f32_16x16x32_bf16(ka1t[t], bq1[u], st[u][t], 0, 0, 0);
                }

            union { uint4 u4; b16x8 v; } bp[2];
            #pragma unroll
            for (int u = 0; u < 2; u++) {
                float p00 = __builtin_amdgcn_exp2f(st[u][0][0] * SC);
                float p01 = __builtin_amdgcn_exp2f(st[u][0][1] * SC);
                float p02 = __builtin_amdgcn_exp2f(st[u][0][2] * SC);
                float p03 = __builtin_amdgcn_exp2f(st[u][0][3] * SC);
                float p10 = __builtin_amdgcn_exp2f(st[u][1][0] * SC);
                float p11 = __builtin_amdgcn_exp2f(st[u][1][1] * SC);
                float p12 = __builtin_amdgcn_exp2f(st[u][1][2] * SC);
                float p13 = __builtin_amdgcn_exp2f(st[u][1][3] * SC);
                Lacc[u] += ((p00 + p01) + (p02 + p03)) + ((p10 + p11) + (p12 + p13));

                const uint pk00 = packbf(p00, p01), pk01 = packbf(p02, p03);
                const uint pk10 = packbf(p10, p11), pk11 = packbf(p12, p13);

                uint a, b, dw0, dw1, dw2, dw3;
                a = __shfl((int)pk00, s0); b = __shfl((int)pk10, s0); dw0 = lowq ? a : b;
                a = __shfl((int)pk01, s0); b = __shfl((int)pk11, s0); dw1 = lowq ? a : b;
                a = __shfl((int)pk00, s1); b = __shfl((int)pk10, s1); dw2 = lowq ? a : b;
                a = __shfl((int)pk01, s1); b = __shfl((int)pk11, s1); dw3 = lowq ? a : b;
                bp[u].u4 = (uint4){dw0, dw1, dw2, dw3};
            }

            #pragma unroll
            for (int dt = 0; dt < 4; dt++) {
                const b16x8 av = *reinterpret_cast<const b16x8*>(
                    &Vs[(dt * 16 + n) * AP + mc * 32 + q * 8]);
                #pragma unroll
                for (int u = 0; u < 2; u++)
                    o[u][dt] = __builtin_amdgcn_mfma_f32_16x16x32_bf16(av, bp[u].v, o[u][dt], 0, 0, 0);
            }
        }
        __syncthreads();
    }

    const int bb = head / 12, h = head - bb * 12;
    #pragma unroll
    for (int u = 0; u < 2; u++) {
        float L = Lacc[u];
        L += __shfl_xor(L, 16);
        L += __shfl_xor(L, 32);
        const float inv = 1.f / L;
        ushort* dst = ao + ((size_t)(bb * 1024 + qrow0 + u * 16 + n)) * 768 + h * 64 + q * 4;
        #pragma unroll
        for (int dt = 0; dt < 4; dt++) {
            ushort4 pk;
            pk.x = f2b(o[u][dt][0] * inv);
            pk.y = f2b(o[u][dt][1] * inv);
            pk.z = f2b(o[u][dt][2] * inv);
            pk.w = f2b(o[u][dt][3] * inv);
            *reinterpret_cast<ushort4*>(dst + dt * 16) = pk;
        }
    }
}

// ---------------- launch ----------------

extern "C" void kernel_launch(void* const* d_in, const int* in_sizes, int n_in,
                              void* d_out, int out_size, void* d_ws, size_t ws_size,
                              hipStream_t stream) {
    (void)in_sizes; (void)n_in; (void)out_size; (void)ws_size;
    const float* x     = (const float*)d_in[0];
    const float* Wqkv  = (const float*)d_in[4];
    const float* Wproj = (const float*)d_in[5];
    const float* bproj = (const float*)d_in[6];
    float* out = (float*)d_out;

    char* ws = (char*)d_ws;
    ushort* wqkvt  = (ushort*)ws; ws += (size_t)2304 * 768 * 2;
    ushort* wprojt = (ushort*)ws; ws += (size_t)768  * 768 * 2;
    ushort* qa     = (ushort*)ws; ws += (size_t)96 * 1024 * 64 * 2;
    ushort* ka     = (ushort*)ws; ws += (size_t)96 * 1024 * 64 * 2;
    ushort* vt     = (ushort*)ws; ws += (size_t)96 * 64 * 1024 * 2;
    ushort* ao     = (ushort*)ws; ws += (size_t)8192 * 768 * 2;

    k_prep<<<dim3(576), dim3(256), 0, stream>>>(Wqkv, wqkvt, Wproj, wprojt);
    k_gemm<0><<<dim3(1152), dim3(256), 0, stream>>>(x, nullptr, wqkvt, qa, ka, vt,
                                                    nullptr, nullptr, 8192, 2304, 768);
    k_attn<<<dim3(768), dim3(256), 0, stream>>>(qa, ka, vt, ao);
    k_gemm<1><<<dim3(384), dim3(256), 0, stream>>>(nullptr, ao, wprojt, nullptr, nullptr, nullptr,
                                                   out, bproj, 8192, 768, 768);
}